// Round 1
// baseline (3625.801 us; speedup 1.0000x reference)
//
#include <hip/hip_runtime.h>

#define NPIX 250000
#define NSUP 50000
#define NE   800000
#define DD   128
#define NL   5

#define BN_EPS_C 1e-5f
#define SLOPE 0.01f
#define INV_C (1.0f / 2.9f)

__device__ __forceinline__ size_t rowoff(int r) { return (size_t)r * DD; }

// ---------------- pooling ----------------
__global__ __launch_bounds__(256) void pool_accum(const float* __restrict__ x,
        const int* __restrict__ seg, float* __restrict__ hsum, float* __restrict__ counts) {
    int t = blockIdx.x * 256 + threadIdx.x;     // NPIX*32 threads
    int p = t >> 5, l = t & 31;
    if (p >= NPIX) return;
    int s = seg[p];
    float4 v = *(const float4*)(x + rowoff(p) + l * 4);
    float* d = hsum + rowoff(s) + l * 4;
    atomicAdd(d + 0, v.x); atomicAdd(d + 1, v.y);
    atomicAdd(d + 2, v.z); atomicAdd(d + 3, v.w);
    if (l == 0) atomicAdd(counts + s, 1.0f);
}

__global__ __launch_bounds__(256) void pool_div(float* __restrict__ h,
        const float* __restrict__ counts) {
    int t = blockIdx.x * 256 + threadIdx.x;     // NSUP*32 threads
    int s = t >> 5, l = t & 31;
    if (s >= NSUP) return;
    float c = fmaxf(counts[s], 1.0f);
    float inv = 1.0f / c;
    float4* p = (float4*)(h + rowoff(s) + l * 4);
    float4 v = *p;
    v.x *= inv; v.y *= inv; v.z *= inv; v.w *= inv;
    *p = v;
}

// ---------------- CSR build (counting sort by dst) ----------------
__global__ __launch_bounds__(256) void edge_hist(const int* __restrict__ dst,
        int* __restrict__ cnt) {
    int e = blockIdx.x * 256 + threadIdx.x;
    if (e >= NE) return;
    atomicAdd(cnt + dst[e], 1);
}

__global__ __launch_bounds__(1024) void scan_rowptr(const int* __restrict__ cnt,
        int* __restrict__ rp) {
    const int T = 1024;
    const int PER = (NSUP + T - 1) / T;         // 49
    int t = threadIdx.x;
    int lo = t * PER, hi = min(lo + PER, NSUP);
    int s = 0;
    for (int i = lo; i < hi; ++i) s += cnt[i];
    __shared__ int ps[T];
    ps[t] = s;
    __syncthreads();
    for (int off = 1; off < T; off <<= 1) {
        int v = (t >= off) ? ps[t - off] : 0;
        __syncthreads();
        ps[t] += v;
        __syncthreads();
    }
    int base = (t == 0) ? 0 : ps[t - 1];
    for (int i = lo; i < hi; ++i) { rp[i] = base; base += cnt[i]; }
    if (t == T - 1) rp[NSUP] = base;
}

__global__ __launch_bounds__(256) void edge_scatter(const int* __restrict__ srcv,
        const int* __restrict__ dstv, const float* __restrict__ w,
        const int* __restrict__ rp, int* __restrict__ fill,
        int* __restrict__ es, float* __restrict__ ew) {
    int e = blockIdx.x * 256 + threadIdx.x;
    if (e >= NE) return;
    int d = dstv[e];
    int pos = rp[d] + atomicAdd(fill + d, 1);
    es[pos] = srcv[e];
    ew[pos] = w[e];
}

// ---------------- GEMM: z = h @ W + b  (tile 32 rows x 128 cols) ----------------
__global__ __launch_bounds__(256) void gemm_bias(const float* __restrict__ hin,
        const float* __restrict__ W, const float* __restrict__ bias, float* __restrict__ z) {
    __shared__ float hs[32 * DD];   // 16 KB
    __shared__ float Ws[64 * DD];   // 32 KB
    const int tid = threadIdx.x;
    const int r0 = blockIdx.x * 32;
    {
        for (int i = tid; i < 32 * DD / 4; i += 256) {
            int row = i >> 5;                   // 32 float4 per row
            float4 v = make_float4(0.f, 0.f, 0.f, 0.f);
            if (r0 + row < NSUP) v = *(const float4*)(hin + rowoff(r0 + row) + (i & 31) * 4);
            *(float4*)(hs + i * 4) = v;
        }
    }
    const int cg = tid & 31;   // 32 col groups of 4
    const int rg = tid >> 5;   // 8 row groups of 4
    float acc[4][4];
    #pragma unroll
    for (int i = 0; i < 4; ++i)
        #pragma unroll
        for (int j = 0; j < 4; ++j) acc[i][j] = 0.f;

    for (int k0 = 0; k0 < DD; k0 += 64) {
        __syncthreads();
        for (int i = tid; i < 64 * DD / 4; i += 256)
            *(float4*)(Ws + i * 4) = *(const float4*)(W + (size_t)k0 * DD + i * 4);
        __syncthreads();
        #pragma unroll 8
        for (int k = 0; k < 64; ++k) {
            float4 wv = *(const float4*)(Ws + k * DD + cg * 4);
            #pragma unroll
            for (int i = 0; i < 4; ++i) {
                float hv = hs[(rg * 4 + i) * DD + k0 + k];
                acc[i][0] = fmaf(hv, wv.x, acc[i][0]);
                acc[i][1] = fmaf(hv, wv.y, acc[i][1]);
                acc[i][2] = fmaf(hv, wv.z, acc[i][2]);
                acc[i][3] = fmaf(hv, wv.w, acc[i][3]);
            }
        }
    }
    float4 bv = *(const float4*)(bias + cg * 4);
    #pragma unroll
    for (int i = 0; i < 4; ++i) {
        int r = r0 + rg * 4 + i;
        if (r < NSUP) {
            float4 o = make_float4(acc[i][0] + bv.x, acc[i][1] + bv.y,
                                   acc[i][2] + bv.z, acc[i][3] + bv.w);
            *(float4*)(z + rowoff(r) + cg * 4) = o;
        }
    }
}

// ---------------- SpMM: out[r] = sum_e w_e * zin[src_e]  (wave per row) ----------------
// MODE 0: out = sum;  MODE 1: out = (sum + xs) * INV_C
template <int MODE>
__global__ __launch_bounds__(256) void spmm_k(const float* __restrict__ zin,
        const int* __restrict__ rp, const int* __restrict__ es, const float* __restrict__ ew,
        const float* __restrict__ xs, float* __restrict__ out) {
    int row = blockIdx.x * 4 + (threadIdx.x >> 6);
    int lane = threadIdx.x & 63;
    int j0 = rp[row], j1 = rp[row + 1];
    float accx = 0.f, accy = 0.f;
    for (int j = j0; j < j1; ++j) {
        int s = es[j];
        float w = ew[j];
        float2 v = *(const float2*)(zin + rowoff(s) + lane * 2);
        accx = fmaf(w, v.x, accx);
        accy = fmaf(w, v.y, accy);
    }
    if (MODE) {
        float2 xv = *(const float2*)(xs + rowoff(row) + lane * 2);
        accx = (accx + xv.x) * INV_C;
        accy = (accy + xv.y) * INV_C;
    }
    float2 o = make_float2(accx, accy);
    *(float2*)(out + rowoff(row) + lane * 2) = o;
}

// ---------------- BatchNorm ----------------
__global__ __launch_bounds__(256) void bn_stats(const float* __restrict__ xi,
        float* __restrict__ sums) {
    int c = threadIdx.x & 127;
    int rh = threadIdx.x >> 7;   // 0/1
    float s = 0.f, q = 0.f;
    for (int r = blockIdx.x * 2 + rh; r < NSUP; r += gridDim.x * 2) {
        float v = xi[rowoff(r) + c];
        s += v;
        q = fmaf(v, v, q);
    }
    __shared__ float ls[256], lq[256];
    ls[threadIdx.x] = s; lq[threadIdx.x] = q;
    __syncthreads();
    if (threadIdx.x < 128) {
        s = ls[threadIdx.x] + ls[threadIdx.x + 128];
        q = lq[threadIdx.x] + lq[threadIdx.x + 128];
        atomicAdd(&sums[c], s);
        atomicAdd(&sums[128 + c], q);
    }
}

__global__ void bn_finalize(const float* __restrict__ sums, const float* __restrict__ gamma,
        const float* __restrict__ beta, float* __restrict__ sc) {
    int c = threadIdx.x;
    float mean = sums[c] * (1.0f / NSUP);
    float var = sums[128 + c] * (1.0f / NSUP) - mean * mean;
    float scale = gamma[c] / sqrtf(var + BN_EPS_C);
    sc[c] = scale;
    sc[128 + c] = beta[c] - mean * scale;
}

__global__ __launch_bounds__(256) void bn_apply(const float* __restrict__ xi,
        const float* __restrict__ sc, float* __restrict__ h) {
    int t = blockIdx.x * 256 + threadIdx.x;     // NSUP*32 threads
    int r = t >> 5, l = t & 31;
    if (r >= NSUP) return;
    float4 v = *(const float4*)(xi + rowoff(r) + l * 4);
    float4 scv = *(const float4*)(sc + l * 4);
    float4 shv = *(const float4*)(sc + 128 + l * 4);
    float o;
    o = fmaf(v.x, scv.x, shv.x); v.x = o > 0.f ? o : SLOPE * o;
    o = fmaf(v.y, scv.y, shv.y); v.y = o > 0.f ? o : SLOPE * o;
    o = fmaf(v.z, scv.z, shv.z); v.z = o > 0.f ? o : SLOPE * o;
    o = fmaf(v.w, scv.w, shv.w); v.w = o > 0.f ? o : SLOPE * o;
    *(float4*)(h + rowoff(r) + l * 4) = v;
}

// ---------------- unpool ----------------
__global__ __launch_bounds__(256) void unpool(const float* __restrict__ h,
        const int* __restrict__ seg, float* __restrict__ out) {
    int t = blockIdx.x * 256 + threadIdx.x;     // NPIX*32 threads
    int p = t >> 5, l = t & 31;
    if (p >= NPIX) return;
    int s = seg[p];
    float4 v = *(const float4*)(h + rowoff(s) + l * 4);
    *(float4*)(out + rowoff(p) + l * 4) = v;
}

extern "C" void kernel_launch(void* const* d_in, const int* in_sizes, int n_in,
                              void* d_out, int out_size, void* d_ws, size_t ws_size,
                              hipStream_t stream) {
    const float* x     = (const float*)d_in[0];
    const float* W     = (const float*)d_in[1];
    const float* b     = (const float*)d_in[2];
    const float* gamma = (const float*)d_in[3];
    const float* beta  = (const float*)d_in[4];
    const float* ewt   = (const float*)d_in[5];
    const int*   seg   = (const int*)d_in[6];
    const int*   eidx  = (const int*)d_in[7];
    const int*   esrc  = eidx;
    const int*   edst  = eidx + NE;
    float* out = (float*)d_out;

    // d_out (128 MB = 4 x 32 MB-ish) hosts the 4 transient [NSUP, DD] matrices;
    // they are all dead before the final unpool overwrites d_out.
    const size_t MAT = (size_t)NSUP * DD;       // 6.4M floats = 25.6 MB
    float* z  = out;                            // 0   .. 25.6 MB
    float* xs = out + MAT;                      // 25.6.. 51.2
    float* xa = out + 2 * MAT;                  // 51.2.. 76.8
    float* xb = out + 3 * MAT;                  // 76.8..102.4  (all < 128 MB)

    // workspace layout
    char* ws = (char*)d_ws;
    size_t off = 0;
    auto alloc = [&](size_t bytes) -> void* {
        void* p = ws + off;
        off = (off + bytes + 255) & ~(size_t)255;
        return p;
    };
    float* h       = (float*)alloc(sizeof(float) * MAT);   // 25.6 MB
    float* counts  = (float*)alloc(sizeof(float) * NSUP);
    int*   rowcnt  = (int*)alloc(sizeof(int) * NSUP);
    int*   rowptr  = (int*)alloc(sizeof(int) * (NSUP + 1));
    int*   rowfill = (int*)alloc(sizeof(int) * NSUP);
    int*   es      = (int*)alloc(sizeof(int) * NE);
    float* ewv     = (float*)alloc(sizeof(float) * NE);
    float* stats   = (float*)alloc(sizeof(float) * 256);
    float* sc      = (float*)alloc(sizeof(float) * 256);

    hipMemsetAsync(h, 0, sizeof(float) * MAT, stream);
    hipMemsetAsync(counts, 0, sizeof(float) * NSUP, stream);
    hipMemsetAsync(rowcnt, 0, sizeof(int) * NSUP, stream);
    hipMemsetAsync(rowfill, 0, sizeof(int) * NSUP, stream);

    // pooling (segment mean)
    pool_accum<<<NPIX * 32 / 256, 256, 0, stream>>>(x, seg, h, counts);
    pool_div<<<NSUP * 32 / 256, 256, 0, stream>>>(h, counts);

    // CSR by dst
    edge_hist<<<(NE + 255) / 256, 256, 0, stream>>>(edst, rowcnt);
    scan_rowptr<<<1, 1024, 0, stream>>>(rowcnt, rowptr);
    edge_scatter<<<(NE + 255) / 256, 256, 0, stream>>>(esrc, edst, ewt, rowptr, rowfill, es, ewv);

    // 5 SFNet layers
    for (int i = 0; i < NL; ++i) {
        gemm_bias<<<(NSUP + 31) / 32, 256, 0, stream>>>(h, W + (size_t)i * DD * DD, b + i * DD, z);
        spmm_k<0><<<NSUP / 4, 256, 0, stream>>>(z, rowptr, es, ewv, nullptr, xs);

        const float* cur = h;
        float* nxt = xa;
        for (int it = 0; it < 5; ++it) {
            spmm_k<1><<<NSUP / 4, 256, 0, stream>>>(cur, rowptr, es, ewv, xs, nxt);
            cur = nxt;
            nxt = (nxt == xa) ? xb : xa;
        }
        // cur == xa after 5 iterations

        hipMemsetAsync(stats, 0, sizeof(float) * 256, stream);
        bn_stats<<<256, 256, 0, stream>>>(cur, stats);
        bn_finalize<<<1, 128, 0, stream>>>(stats, gamma + i * DD, beta + i * DD, sc);
        bn_apply<<<NSUP * 32 / 256, 256, 0, stream>>>(cur, sc, h);
    }

    // unpool (overwrites all of d_out)
    unpool<<<NPIX * 32 / 256, 256, 0, stream>>>(h, seg, out);
}

// Round 2
// 2485.810 us; speedup vs baseline: 1.4586x; 1.4586x over previous
//
#include <hip/hip_runtime.h>

#define NPIX 250000
#define NSUP 50000
#define NE   800000
#define DD   128
#define NL   5

#define BN_EPS_C 1e-5f
#define SLOPE 0.01f
#define INV_C (1.0f / 2.9f)

// padded edge capacity: NE + 3 per row worst case
#define NEPAD (NE + 3 * NSUP)

__device__ __forceinline__ size_t rowoff(int r) { return (size_t)r * DD; }

// ---------------- generic histogram ----------------
__global__ __launch_bounds__(256) void hist_k(const int* __restrict__ ids,
        int* __restrict__ cnt, int n) {
    int e = blockIdx.x * 256 + threadIdx.x;
    if (e >= n) return;
    atomicAdd(cnt + ids[e], 1);
}

// ---------------- single-block scan over NSUP counters (optionally padded) ----------------
template <int PAD>
__global__ __launch_bounds__(1024) void scan_rowptr(const int* __restrict__ cnt,
        int* __restrict__ rp) {
    const int T = 1024;
    const int PER = (NSUP + T - 1) / T;         // 49
    int t = threadIdx.x;
    int lo = t * PER, hi = min(lo + PER, NSUP);
    int s = 0;
    for (int i = lo; i < hi; ++i) {
        int c = cnt[i];
        if (PAD > 1) c = (c + PAD - 1) & ~(PAD - 1);
        s += c;
    }
    __shared__ int ps[T];
    ps[t] = s;
    __syncthreads();
    for (int off = 1; off < T; off <<= 1) {
        int v = (t >= off) ? ps[t - off] : 0;
        __syncthreads();
        ps[t] += v;
        __syncthreads();
    }
    int base = (t == 0) ? 0 : ps[t - 1];
    for (int i = lo; i < hi; ++i) {
        rp[i] = base;
        int c = cnt[i];
        if (PAD > 1) c = (c + PAD - 1) & ~(PAD - 1);
        base += c;
    }
    if (t == T - 1) rp[NSUP] = base;
}

// ---------------- pixel scatter (pixel-CSR by superpixel) ----------------
__global__ __launch_bounds__(256) void pix_scatter(const int* __restrict__ seg,
        const int* __restrict__ rp, int* __restrict__ fill, int* __restrict__ pix) {
    int p = blockIdx.x * 256 + threadIdx.x;
    if (p >= NPIX) return;
    int s = seg[p];
    int pos = rp[s] + atomicAdd(fill + s, 1);
    pix[pos] = p;
}

// ---------------- edge scatter ----------------
__global__ __launch_bounds__(256) void edge_scatter(const int* __restrict__ srcv,
        const int* __restrict__ dstv, const float* __restrict__ w,
        const int* __restrict__ rp, int* __restrict__ fill,
        int* __restrict__ es, float* __restrict__ ew) {
    int e = blockIdx.x * 256 + threadIdx.x;
    if (e >= NE) return;
    int d = dstv[e];
    int pos = rp[d] + atomicAdd(fill + d, 1);
    es[pos] = srcv[e];
    ew[pos] = w[e];
}

// ---------------- pooling: wave per superpixel, gather member pixel rows ----------------
__global__ __launch_bounds__(256) void pool_gather(const float* __restrict__ x,
        const int* __restrict__ pp, const int* __restrict__ pix, float* __restrict__ h) {
    int row = blockIdx.x * 4 + (threadIdx.x >> 6);
    int lane = threadIdx.x & 63;
    int j0 = pp[row], j1 = pp[row + 1];
    float ax = 0.f, ay = 0.f;
    for (int j = j0; j < j1; ++j) {
        int p = pix[j];
        float2 v = *(const float2*)(x + rowoff(p) + lane * 2);
        ax += v.x; ay += v.y;
    }
    float inv = 1.0f / fmaxf((float)(j1 - j0), 1.0f);
    *(float2*)(h + rowoff(row) + lane * 2) = make_float2(ax * inv, ay * inv);
}

// ---------------- GEMM: z = h @ W + b  (tile 32 rows x 128 cols) ----------------
__global__ __launch_bounds__(256) void gemm_bias(const float* __restrict__ hin,
        const float* __restrict__ W, const float* __restrict__ bias, float* __restrict__ z) {
    __shared__ float hs[32 * DD];   // 16 KB
    __shared__ float Ws[64 * DD];   // 32 KB
    const int tid = threadIdx.x;
    const int r0 = blockIdx.x * 32;
    {
        for (int i = tid; i < 32 * DD / 4; i += 256) {
            int row = i >> 5;
            float4 v = make_float4(0.f, 0.f, 0.f, 0.f);
            if (r0 + row < NSUP) v = *(const float4*)(hin + rowoff(r0 + row) + (i & 31) * 4);
            *(float4*)(hs + i * 4) = v;
        }
    }
    const int cg = tid & 31;
    const int rg = tid >> 5;
    float acc[4][4];
    #pragma unroll
    for (int i = 0; i < 4; ++i)
        #pragma unroll
        for (int j = 0; j < 4; ++j) acc[i][j] = 0.f;

    for (int k0 = 0; k0 < DD; k0 += 64) {
        __syncthreads();
        for (int i = tid; i < 64 * DD / 4; i += 256)
            *(float4*)(Ws + i * 4) = *(const float4*)(W + (size_t)k0 * DD + i * 4);
        __syncthreads();
        #pragma unroll 8
        for (int k = 0; k < 64; ++k) {
            float4 wv = *(const float4*)(Ws + k * DD + cg * 4);
            #pragma unroll
            for (int i = 0; i < 4; ++i) {
                float hv = hs[(rg * 4 + i) * DD + k0 + k];
                acc[i][0] = fmaf(hv, wv.x, acc[i][0]);
                acc[i][1] = fmaf(hv, wv.y, acc[i][1]);
                acc[i][2] = fmaf(hv, wv.z, acc[i][2]);
                acc[i][3] = fmaf(hv, wv.w, acc[i][3]);
            }
        }
    }
    float4 bv = *(const float4*)(bias + cg * 4);
    #pragma unroll
    for (int i = 0; i < 4; ++i) {
        int r = r0 + rg * 4 + i;
        if (r < NSUP) {
            float4 o = make_float4(acc[i][0] + bv.x, acc[i][1] + bv.y,
                                   acc[i][2] + bv.z, acc[i][3] + bv.w);
            *(float4*)(z + rowoff(r) + cg * 4) = o;
        }
    }
}

// ---------------- SpMM: wave per row, 4 edges per iteration (padded CSR) ----------------
// MODE 0: out = sum;  MODE 1: out = (sum + xs) * INV_C
template <int MODE>
__global__ __launch_bounds__(256) void spmm_k(const float* __restrict__ zin,
        const int* __restrict__ rp, const int* __restrict__ es, const float* __restrict__ ew,
        const float* __restrict__ xs, float* __restrict__ out) {
    int row = blockIdx.x * 4 + (threadIdx.x >> 6);
    int lane = threadIdx.x & 63;
    int j0 = rp[row], j1 = rp[row + 1];
    float ax = 0.f, ay = 0.f, bx = 0.f, by = 0.f;
    for (int j = j0; j < j1; j += 4) {
        int4   s4 = *(const int4*)(es + j);
        float4 w4 = *(const float4*)(ew + j);
        float2 v0 = *(const float2*)(zin + rowoff(s4.x) + lane * 2);
        float2 v1 = *(const float2*)(zin + rowoff(s4.y) + lane * 2);
        float2 v2 = *(const float2*)(zin + rowoff(s4.z) + lane * 2);
        float2 v3 = *(const float2*)(zin + rowoff(s4.w) + lane * 2);
        ax = fmaf(w4.x, v0.x, ax); ay = fmaf(w4.x, v0.y, ay);
        bx = fmaf(w4.y, v1.x, bx); by = fmaf(w4.y, v1.y, by);
        ax = fmaf(w4.z, v2.x, ax); ay = fmaf(w4.z, v2.y, ay);
        bx = fmaf(w4.w, v3.x, bx); by = fmaf(w4.w, v3.y, by);
    }
    float accx = ax + bx, accy = ay + by;
    if (MODE) {
        float2 xv = *(const float2*)(xs + rowoff(row) + lane * 2);
        accx = (accx + xv.x) * INV_C;
        accy = (accy + xv.y) * INV_C;
    }
    *(float2*)(out + rowoff(row) + lane * 2) = make_float2(accx, accy);
}

// ---------------- BatchNorm ----------------
__global__ __launch_bounds__(256) void bn_stats(const float* __restrict__ xi,
        float* __restrict__ sums) {
    int c = threadIdx.x & 127;
    int rh = threadIdx.x >> 7;
    float s = 0.f, q = 0.f;
    for (int r = blockIdx.x * 2 + rh; r < NSUP; r += gridDim.x * 2) {
        float v = xi[rowoff(r) + c];
        s += v;
        q = fmaf(v, v, q);
    }
    __shared__ float ls[256], lq[256];
    ls[threadIdx.x] = s; lq[threadIdx.x] = q;
    __syncthreads();
    if (threadIdx.x < 128) {
        s = ls[threadIdx.x] + ls[threadIdx.x + 128];
        q = lq[threadIdx.x] + lq[threadIdx.x + 128];
        atomicAdd(&sums[c], s);
        atomicAdd(&sums[128 + c], q);
    }
}

__global__ void bn_finalize(const float* __restrict__ sums, const float* __restrict__ gamma,
        const float* __restrict__ beta, float* __restrict__ sc) {
    int c = threadIdx.x;
    float mean = sums[c] * (1.0f / NSUP);
    float var = sums[128 + c] * (1.0f / NSUP) - mean * mean;
    float scale = gamma[c] / sqrtf(var + BN_EPS_C);
    sc[c] = scale;
    sc[128 + c] = beta[c] - mean * scale;
}

__global__ __launch_bounds__(256) void bn_apply(const float* __restrict__ xi,
        const float* __restrict__ sc, float* __restrict__ h) {
    int t = blockIdx.x * 256 + threadIdx.x;
    int r = t >> 5, l = t & 31;
    if (r >= NSUP) return;
    float4 v = *(const float4*)(xi + rowoff(r) + l * 4);
    float4 scv = *(const float4*)(sc + l * 4);
    float4 shv = *(const float4*)(sc + 128 + l * 4);
    float o;
    o = fmaf(v.x, scv.x, shv.x); v.x = o > 0.f ? o : SLOPE * o;
    o = fmaf(v.y, scv.y, shv.y); v.y = o > 0.f ? o : SLOPE * o;
    o = fmaf(v.z, scv.z, shv.z); v.z = o > 0.f ? o : SLOPE * o;
    o = fmaf(v.w, scv.w, shv.w); v.w = o > 0.f ? o : SLOPE * o;
    *(float4*)(h + rowoff(r) + l * 4) = v;
}

// ---------------- unpool ----------------
__global__ __launch_bounds__(256) void unpool(const float* __restrict__ h,
        const int* __restrict__ seg, float* __restrict__ out) {
    int t = blockIdx.x * 256 + threadIdx.x;
    int p = t >> 5, l = t & 31;
    if (p >= NPIX) return;
    int s = seg[p];
    float4 v = *(const float4*)(h + rowoff(s) + l * 4);
    *(float4*)(out + rowoff(p) + l * 4) = v;
}

extern "C" void kernel_launch(void* const* d_in, const int* in_sizes, int n_in,
                              void* d_out, int out_size, void* d_ws, size_t ws_size,
                              hipStream_t stream) {
    const float* x     = (const float*)d_in[0];
    const float* W     = (const float*)d_in[1];
    const float* b     = (const float*)d_in[2];
    const float* gamma = (const float*)d_in[3];
    const float* beta  = (const float*)d_in[4];
    const float* ewt   = (const float*)d_in[5];
    const int*   seg   = (const int*)d_in[6];
    const int*   eidx  = (const int*)d_in[7];
    const int*   esrc  = eidx;
    const int*   edst  = eidx + NE;
    float* out = (float*)d_out;

    // d_out (128 MB) hosts the 4 transient [NSUP, DD] matrices; all dead
    // before the final unpool overwrites d_out.
    const size_t MAT = (size_t)NSUP * DD;       // 25.6 MB
    float* z  = out;
    float* xs = out + MAT;
    float* xa = out + 2 * MAT;
    float* xb = out + 3 * MAT;

    char* ws = (char*)d_ws;
    size_t off = 0;
    auto alloc = [&](size_t bytes) -> void* {
        void* p = ws + off;
        off = (off + bytes + 255) & ~(size_t)255;
        return p;
    };
    float* h       = (float*)alloc(sizeof(float) * MAT);       // 25.6 MB
    int*   rowcnt  = (int*)alloc(sizeof(int) * NSUP);
    int*   rowptr  = (int*)alloc(sizeof(int) * (NSUP + 1));
    int*   rowfill = (int*)alloc(sizeof(int) * NSUP);
    int*   pixcnt  = (int*)alloc(sizeof(int) * NSUP);
    int*   pixptr  = (int*)alloc(sizeof(int) * (NSUP + 1));
    int*   pixfill = (int*)alloc(sizeof(int) * NSUP);
    int*   pixids  = (int*)alloc(sizeof(int) * NPIX);          // 1 MB
    int*   es      = (int*)alloc(sizeof(int) * NEPAD);         // 3.8 MB
    float* ewv     = (float*)alloc(sizeof(float) * NEPAD);     // 3.8 MB
    float* stats   = (float*)alloc(sizeof(float) * 256);
    float* sc      = (float*)alloc(sizeof(float) * 256);

    hipMemsetAsync(rowcnt, 0, sizeof(int) * NSUP, stream);
    hipMemsetAsync(rowfill, 0, sizeof(int) * NSUP, stream);
    hipMemsetAsync(pixcnt, 0, sizeof(int) * NSUP, stream);
    hipMemsetAsync(pixfill, 0, sizeof(int) * NSUP, stream);
    hipMemsetAsync(es, 0, sizeof(int) * NEPAD, stream);        // padding -> src 0
    hipMemsetAsync(ewv, 0, sizeof(float) * NEPAD, stream);     // padding -> w 0.0f

    // pixel CSR + pooling (segment mean), no atomics on feature data
    hist_k<<<(NPIX + 255) / 256, 256, 0, stream>>>(seg, pixcnt, NPIX);
    scan_rowptr<1><<<1, 1024, 0, stream>>>(pixcnt, pixptr);
    pix_scatter<<<(NPIX + 255) / 256, 256, 0, stream>>>(seg, pixptr, pixfill, pixids);
    pool_gather<<<NSUP / 4, 256, 0, stream>>>(x, pixptr, pixids, h);

    // edge CSR by dst, rows padded to multiple of 4
    hist_k<<<(NE + 255) / 256, 256, 0, stream>>>(edst, rowcnt, NE);
    scan_rowptr<4><<<1, 1024, 0, stream>>>(rowcnt, rowptr);
    edge_scatter<<<(NE + 255) / 256, 256, 0, stream>>>(esrc, edst, ewt, rowptr, rowfill, es, ewv);

    // 5 SFNet layers
    for (int i = 0; i < NL; ++i) {
        gemm_bias<<<(NSUP + 31) / 32, 256, 0, stream>>>(h, W + (size_t)i * DD * DD, b + i * DD, z);
        spmm_k<0><<<NSUP / 4, 256, 0, stream>>>(z, rowptr, es, ewv, nullptr, xs);

        const float* cur = h;
        float* nxt = xa;
        for (int it = 0; it < 5; ++it) {
            spmm_k<1><<<NSUP / 4, 256, 0, stream>>>(cur, rowptr, es, ewv, xs, nxt);
            cur = nxt;
            nxt = (nxt == xa) ? xb : xa;
        }
        // cur == xa after 5 iterations

        hipMemsetAsync(stats, 0, sizeof(float) * 256, stream);
        bn_stats<<<256, 256, 0, stream>>>(cur, stats);
        bn_finalize<<<1, 128, 0, stream>>>(stats, gamma + i * DD, beta + i * DD, sc);
        bn_apply<<<NSUP * 32 / 256, 256, 0, stream>>>(cur, sc, h);
    }

    // unpool (overwrites all of d_out)
    unpool<<<NPIX * 32 / 256, 256, 0, stream>>>(h, seg, out);
}

// Round 3
// 1572.848 us; speedup vs baseline: 2.3052x; 1.5805x over previous
//
#include <hip/hip_runtime.h>

#define NPIX 250000
#define NSUP 50000
#define NE   800000
#define DD   128
#define NL   5

#define BN_EPS_C 1e-5f
#define SLOPE 0.01f
#define INV_C (1.0f / 2.9f)

// padded edge capacity: NE + 3 per row worst case
#define NEPAD (NE + 3 * NSUP)
// scan geometry: 1024 threads x 52 elements (52 % 4 == 0), covers 53248 >= NSUP
#define SCAN_PER 52
#define CNT_CAP (1024 * SCAN_PER)

__device__ __forceinline__ size_t rowoff(int r) { return (size_t)r * DD; }

// round-to-nearest-even f32 -> bf16 bits
__device__ __forceinline__ unsigned short f2bf(float f) {
    unsigned int u = __float_as_uint(f);
    unsigned int r = (u + 0x7FFFu + ((u >> 16) & 1u)) >> 16;
    return (unsigned short)r;
}
__device__ __forceinline__ float bf2f_lo(unsigned int v) { return __uint_as_float(v << 16); }
__device__ __forceinline__ float bf2f_hi(unsigned int v) { return __uint_as_float(v & 0xFFFF0000u); }

// ---------------- generic histogram ----------------
__global__ __launch_bounds__(256) void hist_k(const int* __restrict__ ids,
        int* __restrict__ cnt, int n) {
    int e = blockIdx.x * 256 + threadIdx.x;
    if (e >= n) return;
    atomicAdd(cnt + ids[e], 1);
}

// ---------------- single-block scan over padded counters ----------------
// cnt must be CNT_CAP ints, zero beyond NSUP. Rounds each count up to PAD.
template <int PAD>
__global__ __launch_bounds__(1024) void scan_rowptr(const int* __restrict__ cnt,
        int* __restrict__ rp) {
    const int t = threadIdx.x;
    const int lo = t * SCAN_PER;
    int4 c[SCAN_PER / 4];
    int s = 0;
    #pragma unroll
    for (int k = 0; k < SCAN_PER / 4; ++k) {
        int4 v = *(const int4*)(cnt + lo + k * 4);
        if (PAD > 1) {
            v.x = (v.x + PAD - 1) & ~(PAD - 1);
            v.y = (v.y + PAD - 1) & ~(PAD - 1);
            v.z = (v.z + PAD - 1) & ~(PAD - 1);
            v.w = (v.w + PAD - 1) & ~(PAD - 1);
        }
        c[k] = v;
        s += v.x + v.y + v.z + v.w;
    }
    // wave-level inclusive scan (wave = 64)
    int lane = t & 63, wid = t >> 6;
    int v = s;
    #pragma unroll
    for (int d = 1; d < 64; d <<= 1) {
        int u = __shfl_up(v, d);
        if (lane >= d) v += u;
    }
    __shared__ int wtot[16], woff[16];
    if (lane == 63) wtot[wid] = v;
    __syncthreads();
    if (t == 0) {
        int acc = 0;
        #pragma unroll
        for (int w = 0; w < 16; ++w) { woff[w] = acc; acc += wtot[w]; }
    }
    __syncthreads();
    int base = woff[wid] + v - s;   // exclusive prefix for this thread
    #pragma unroll
    for (int k = 0; k < SCAN_PER / 4; ++k) {
        int i = lo + k * 4;
        if (i     <= NSUP) rp[i]     = base;  base += c[k].x;
        if (i + 1 <= NSUP) rp[i + 1] = base;  base += c[k].y;
        if (i + 2 <= NSUP) rp[i + 2] = base;  base += c[k].z;
        if (i + 3 <= NSUP) rp[i + 3] = base;  base += c[k].w;
    }
}

// ---------------- pixel scatter (pixel-CSR by superpixel) ----------------
__global__ __launch_bounds__(256) void pix_scatter(const int* __restrict__ seg,
        const int* __restrict__ rp, int* __restrict__ fill, int* __restrict__ pix) {
    int p = blockIdx.x * 256 + threadIdx.x;
    if (p >= NPIX) return;
    int s = seg[p];
    int pos = rp[s] + atomicAdd(fill + s, 1);
    pix[pos] = p;
}

// ---------------- edge scatter ----------------
__global__ __launch_bounds__(256) void edge_scatter(const int* __restrict__ srcv,
        const int* __restrict__ dstv, const float* __restrict__ w,
        const int* __restrict__ rp, int* __restrict__ fill,
        int* __restrict__ es, float* __restrict__ ew) {
    int e = blockIdx.x * 256 + threadIdx.x;
    if (e >= NE) return;
    int d = dstv[e];
    int pos = rp[d] + atomicAdd(fill + d, 1);
    es[pos] = srcv[e];
    ew[pos] = w[e];
}

// ---------------- pooling: wave per superpixel ----------------
__global__ __launch_bounds__(256) void pool_gather(const float* __restrict__ x,
        const int* __restrict__ pp, const int* __restrict__ pix, float* __restrict__ h) {
    int row = blockIdx.x * 4 + (threadIdx.x >> 6);
    int lane = threadIdx.x & 63;
    int j0 = pp[row], j1 = pp[row + 1];
    float ax = 0.f, ay = 0.f;
    for (int j = j0; j < j1; ++j) {
        int p = pix[j];
        float2 v = *(const float2*)(x + rowoff(p) + lane * 2);
        ax += v.x; ay += v.y;
    }
    float inv = 1.0f / fmaxf((float)(j1 - j0), 1.0f);
    *(float2*)(h + rowoff(row) + lane * 2) = make_float2(ax * inv, ay * inv);
}

// ---------------- GEMM: z = h @ W + b ; also y0 = bf16(h + z) ----------------
__global__ __launch_bounds__(256) void gemm_bias(const float* __restrict__ hin,
        const float* __restrict__ W, const float* __restrict__ bias,
        float* __restrict__ z, unsigned short* __restrict__ y0) {
    __shared__ float hs[32 * DD];   // 16 KB
    __shared__ float Ws[64 * DD];   // 32 KB
    const int tid = threadIdx.x;
    const int r0 = blockIdx.x * 32;
    {
        for (int i = tid; i < 32 * DD / 4; i += 256) {
            int row = i >> 5;
            float4 v = make_float4(0.f, 0.f, 0.f, 0.f);
            if (r0 + row < NSUP) v = *(const float4*)(hin + rowoff(r0 + row) + (i & 31) * 4);
            *(float4*)(hs + i * 4) = v;
        }
    }
    const int cg = tid & 31;
    const int rg = tid >> 5;
    float acc[4][4];
    #pragma unroll
    for (int i = 0; i < 4; ++i)
        #pragma unroll
        for (int j = 0; j < 4; ++j) acc[i][j] = 0.f;

    for (int k0 = 0; k0 < DD; k0 += 64) {
        __syncthreads();
        for (int i = tid; i < 64 * DD / 4; i += 256)
            *(float4*)(Ws + i * 4) = *(const float4*)(W + (size_t)k0 * DD + i * 4);
        __syncthreads();
        #pragma unroll 8
        for (int k = 0; k < 64; ++k) {
            float4 wv = *(const float4*)(Ws + k * DD + cg * 4);
            #pragma unroll
            for (int i = 0; i < 4; ++i) {
                float hv = hs[(rg * 4 + i) * DD + k0 + k];
                acc[i][0] = fmaf(hv, wv.x, acc[i][0]);
                acc[i][1] = fmaf(hv, wv.y, acc[i][1]);
                acc[i][2] = fmaf(hv, wv.z, acc[i][2]);
                acc[i][3] = fmaf(hv, wv.w, acc[i][3]);
            }
        }
    }
    float4 bv = *(const float4*)(bias + cg * 4);
    #pragma unroll
    for (int i = 0; i < 4; ++i) {
        int r = r0 + rg * 4 + i;
        if (r < NSUP) {
            float4 o = make_float4(acc[i][0] + bv.x, acc[i][1] + bv.y,
                                   acc[i][2] + bv.z, acc[i][3] + bv.w);
            *(float4*)(z + rowoff(r) + cg * 4) = o;
            // y0 = h + z (bf16)
            float h0 = hs[(rg * 4 + i) * DD + cg * 4 + 0];
            float h1 = hs[(rg * 4 + i) * DD + cg * 4 + 1];
            float h2 = hs[(rg * 4 + i) * DD + cg * 4 + 2];
            float h3 = hs[(rg * 4 + i) * DD + cg * 4 + 3];
            unsigned int p0 = (unsigned int)f2bf(h0 + o.x) | ((unsigned int)f2bf(h1 + o.y) << 16);
            unsigned int p1 = (unsigned int)f2bf(h2 + o.z) | ((unsigned int)f2bf(h3 + o.w) << 16);
            uint2 pk = make_uint2(p0, p1);
            *(uint2*)(y0 + rowoff(r) + cg * 4) = pk;
        }
    }
}

// ---------------- SpMM over bf16 operand, wave per row, 4-edge packets ----------------
// FINAL=0: yout = bf16( (A@y)*INV_C + z )    (propagate y_{t+1} = xi_{t+1} + z)
// FINAL=1: xi5  = (A@y)*INV_C                (f32, feeds BN)
template <int FINAL>
__global__ __launch_bounds__(256) void spmm_bf(const unsigned short* __restrict__ yin,
        const int* __restrict__ rp, const int* __restrict__ es, const float* __restrict__ ew,
        const float* __restrict__ z, float* __restrict__ xi5, unsigned short* __restrict__ yout) {
    int row = blockIdx.x * 4 + (threadIdx.x >> 6);
    int lane = threadIdx.x & 63;
    int j0 = rp[row], j1 = rp[row + 1];
    float ax = 0.f, ay = 0.f, bx = 0.f, by = 0.f;
    for (int j = j0; j < j1; j += 4) {
        int4   s4 = *(const int4*)(es + j);
        float4 w4 = *(const float4*)(ew + j);
        unsigned int v0 = *(const unsigned int*)(yin + rowoff(s4.x) + lane * 2);
        unsigned int v1 = *(const unsigned int*)(yin + rowoff(s4.y) + lane * 2);
        unsigned int v2 = *(const unsigned int*)(yin + rowoff(s4.z) + lane * 2);
        unsigned int v3 = *(const unsigned int*)(yin + rowoff(s4.w) + lane * 2);
        ax = fmaf(w4.x, bf2f_lo(v0), ax); ay = fmaf(w4.x, bf2f_hi(v0), ay);
        bx = fmaf(w4.y, bf2f_lo(v1), bx); by = fmaf(w4.y, bf2f_hi(v1), by);
        ax = fmaf(w4.z, bf2f_lo(v2), ax); ay = fmaf(w4.z, bf2f_hi(v2), ay);
        bx = fmaf(w4.w, bf2f_lo(v3), bx); by = fmaf(w4.w, bf2f_hi(v3), by);
    }
    float accx = (ax + bx) * INV_C, accy = (ay + by) * INV_C;
    if (FINAL) {
        *(float2*)(xi5 + rowoff(row) + lane * 2) = make_float2(accx, accy);
    } else {
        float2 zv = *(const float2*)(z + rowoff(row) + lane * 2);
        float yx = accx + zv.x, yy = accy + zv.y;
        unsigned int p = (unsigned int)f2bf(yx) | ((unsigned int)f2bf(yy) << 16);
        *(unsigned int*)(yout + rowoff(row) + lane * 2) = p;
    }
}

// ---------------- BatchNorm ----------------
__global__ __launch_bounds__(256) void bn_stats(const float* __restrict__ xi,
        float* __restrict__ sums) {
    int c = threadIdx.x & 127;
    int rh = threadIdx.x >> 7;
    float s = 0.f, q = 0.f;
    for (int r = blockIdx.x * 2 + rh; r < NSUP; r += gridDim.x * 2) {
        float v = xi[rowoff(r) + c];
        s += v;
        q = fmaf(v, v, q);
    }
    __shared__ float ls[256], lq[256];
    ls[threadIdx.x] = s; lq[threadIdx.x] = q;
    __syncthreads();
    if (threadIdx.x < 128) {
        s = ls[threadIdx.x] + ls[threadIdx.x + 128];
        q = lq[threadIdx.x] + lq[threadIdx.x + 128];
        atomicAdd(&sums[c], s);
        atomicAdd(&sums[128 + c], q);
    }
}

__global__ void bn_finalize(const float* __restrict__ sums, const float* __restrict__ gamma,
        const float* __restrict__ beta, float* __restrict__ sc) {
    int c = threadIdx.x;
    float mean = sums[c] * (1.0f / NSUP);
    float var = sums[128 + c] * (1.0f / NSUP) - mean * mean;
    float scale = gamma[c] / sqrtf(var + BN_EPS_C);
    sc[c] = scale;
    sc[128 + c] = beta[c] - mean * scale;
}

__global__ __launch_bounds__(256) void bn_apply(const float* __restrict__ xi,
        const float* __restrict__ sc, float* __restrict__ h) {
    int t = blockIdx.x * 256 + threadIdx.x;
    int r = t >> 5, l = t & 31;
    if (r >= NSUP) return;
    float4 v = *(const float4*)(xi + rowoff(r) + l * 4);
    float4 scv = *(const float4*)(sc + l * 4);
    float4 shv = *(const float4*)(sc + 128 + l * 4);
    float o;
    o = fmaf(v.x, scv.x, shv.x); v.x = o > 0.f ? o : SLOPE * o;
    o = fmaf(v.y, scv.y, shv.y); v.y = o > 0.f ? o : SLOPE * o;
    o = fmaf(v.z, scv.z, shv.z); v.z = o > 0.f ? o : SLOPE * o;
    o = fmaf(v.w, scv.w, shv.w); v.w = o > 0.f ? o : SLOPE * o;
    *(float4*)(h + rowoff(r) + l * 4) = v;
}

// ---------------- unpool ----------------
__global__ __launch_bounds__(256) void unpool(const float* __restrict__ h,
        const int* __restrict__ seg, float* __restrict__ out) {
    int t = blockIdx.x * 256 + threadIdx.x;
    int p = t >> 5, l = t & 31;
    if (p >= NPIX) return;
    int s = seg[p];
    float4 v = *(const float4*)(h + rowoff(s) + l * 4);
    *(float4*)(out + rowoff(p) + l * 4) = v;
}

extern "C" void kernel_launch(void* const* d_in, const int* in_sizes, int n_in,
                              void* d_out, int out_size, void* d_ws, size_t ws_size,
                              hipStream_t stream) {
    const float* x     = (const float*)d_in[0];
    const float* W     = (const float*)d_in[1];
    const float* b     = (const float*)d_in[2];
    const float* gamma = (const float*)d_in[3];
    const float* beta  = (const float*)d_in[4];
    const float* ewt   = (const float*)d_in[5];
    const int*   seg   = (const int*)d_in[6];
    const int*   eidx  = (const int*)d_in[7];
    const int*   esrc  = eidx;
    const int*   edst  = eidx + NE;
    float* out = (float*)d_out;

    // d_out (128 MB) hosts the transients; all dead before the final unpool.
    const size_t MAT = (size_t)NSUP * DD;               // 6.4M elems
    float* z   = out;                                   // f32, 25.6 MB
    float* xi5 = out + MAT;                             // f32, 25.6 MB
    unsigned short* ya = (unsigned short*)(out + 2 * MAT);  // bf16, 12.8 MB
    unsigned short* yb = ya + MAT;                          // bf16, 12.8 MB

    char* ws = (char*)d_ws;
    size_t off = 0;
    auto alloc = [&](size_t bytes) -> void* {
        void* p = ws + off;
        off = (off + bytes + 255) & ~(size_t)255;
        return p;
    };
    float* h       = (float*)alloc(sizeof(float) * MAT);       // 25.6 MB
    int*   rowcnt  = (int*)alloc(sizeof(int) * CNT_CAP);       // zero-padded for scan
    int*   rowptr  = (int*)alloc(sizeof(int) * (NSUP + 1));
    int*   rowfill = (int*)alloc(sizeof(int) * NSUP);
    int*   pixcnt  = (int*)alloc(sizeof(int) * CNT_CAP);
    int*   pixptr  = (int*)alloc(sizeof(int) * (NSUP + 1));
    int*   pixfill = (int*)alloc(sizeof(int) * NSUP);
    int*   pixids  = (int*)alloc(sizeof(int) * NPIX);          // 1 MB
    int*   es      = (int*)alloc(sizeof(int) * NEPAD);         // 3.8 MB
    float* ewv     = (float*)alloc(sizeof(float) * NEPAD);     // 3.8 MB
    float* stats   = (float*)alloc(sizeof(float) * 256);
    float* sc      = (float*)alloc(sizeof(float) * 256);

    hipMemsetAsync(rowcnt, 0, sizeof(int) * CNT_CAP, stream);
    hipMemsetAsync(rowfill, 0, sizeof(int) * NSUP, stream);
    hipMemsetAsync(pixcnt, 0, sizeof(int) * CNT_CAP, stream);
    hipMemsetAsync(pixfill, 0, sizeof(int) * NSUP, stream);
    hipMemsetAsync(es, 0, sizeof(int) * NEPAD, stream);        // padding -> src 0
    hipMemsetAsync(ewv, 0, sizeof(float) * NEPAD, stream);     // padding -> w 0.0f

    // pixel CSR + pooling (segment mean)
    hist_k<<<(NPIX + 255) / 256, 256, 0, stream>>>(seg, pixcnt, NPIX);
    scan_rowptr<1><<<1, 1024, 0, stream>>>(pixcnt, pixptr);
    pix_scatter<<<(NPIX + 255) / 256, 256, 0, stream>>>(seg, pixptr, pixfill, pixids);
    pool_gather<<<NSUP / 4, 256, 0, stream>>>(x, pixptr, pixids, h);

    // edge CSR by dst, rows padded to multiple of 4
    hist_k<<<(NE + 255) / 256, 256, 0, stream>>>(edst, rowcnt, NE);
    scan_rowptr<4><<<1, 1024, 0, stream>>>(rowcnt, rowptr);
    edge_scatter<<<(NE + 255) / 256, 256, 0, stream>>>(esrc, edst, ewt, rowptr, rowfill, es, ewv);

    // 5 SFNet layers.  Identity: xi_{t+1} = A(xi_t + z)/c, so propagate
    // y_t = xi_t + z (bf16) and never materialize x_start.
    for (int i = 0; i < NL; ++i) {
        gemm_bias<<<(NSUP + 31) / 32, 256, 0, stream>>>(h, W + (size_t)i * DD * DD,
                                                        b + i * DD, z, ya);
        // 4 propagate iterations producing y_{t+1}, then final producing xi5
        const unsigned short* ycur = ya;
        unsigned short* ynxt = yb;
        for (int t = 0; t < 4; ++t) {
            spmm_bf<0><<<NSUP / 4, 256, 0, stream>>>(ycur, rowptr, es, ewv, z, nullptr, ynxt);
            const unsigned short* tmp = ycur;
            ycur = ynxt;
            ynxt = (unsigned short*)tmp;
        }
        spmm_bf<1><<<NSUP / 4, 256, 0, stream>>>(ycur, rowptr, es, ewv, nullptr, xi5, nullptr);

        hipMemsetAsync(stats, 0, sizeof(float) * 256, stream);
        bn_stats<<<256, 256, 0, stream>>>(xi5, stats);
        bn_finalize<<<1, 128, 0, stream>>>(stats, gamma + i * DD, beta + i * DD, sc);
        bn_apply<<<NSUP * 32 / 256, 256, 0, stream>>>(xi5, sc, h);
    }

    // unpool (overwrites all of d_out)
    unpool<<<NPIX * 32 / 256, 256, 0, stream>>>(h, seg, out);
}

// Round 4
// 1401.712 us; speedup vs baseline: 2.5867x; 1.1221x over previous
//
#include <hip/hip_runtime.h>

#define NPIX 250000
#define NSUP 50000
#define NE   800000
#define DD   128
#define NL   5

#define BN_EPS_C 1e-5f
#define SLOPE 0.01f
#define INV_C (1.0f / 2.9f)

// edge capacity with per-row pad to multiple of 2
#define NEPAD2 (NE + NSUP)
// scan geometry: 1024 threads x 52 elements, covers 53248 >= NSUP
#define SCAN_PER 52
#define CNT_CAP (1024 * SCAN_PER)

__device__ __forceinline__ size_t rowoff(int r) { return (size_t)r * DD; }

// round-to-nearest-even f32 -> bf16 bits
__device__ __forceinline__ unsigned short f2bf(float f) {
    unsigned int u = __float_as_uint(f);
    unsigned int r = (u + 0x7FFFu + ((u >> 16) & 1u)) >> 16;
    return (unsigned short)r;
}
__device__ __forceinline__ float bf2f_lo(unsigned int v) { return __uint_as_float(v << 16); }
__device__ __forceinline__ float bf2f_hi(unsigned int v) { return __uint_as_float(v & 0xFFFF0000u); }
__device__ __forceinline__ float lrelu(float o) { return o > 0.f ? o : SLOPE * o; }

// ---------------- generic histogram ----------------
__global__ __launch_bounds__(256) void hist_k(const int* __restrict__ ids,
        int* __restrict__ cnt, int n) {
    int e = blockIdx.x * 256 + threadIdx.x;
    if (e >= n) return;
    atomicAdd(cnt + ids[e], 1);
}

// ---------------- single-block scan over padded counters ----------------
template <int PAD>
__global__ __launch_bounds__(1024) void scan_rowptr(const int* __restrict__ cnt,
        int* __restrict__ rp) {
    const int t = threadIdx.x;
    const int lo = t * SCAN_PER;
    int4 c[SCAN_PER / 4];
    int s = 0;
    #pragma unroll
    for (int k = 0; k < SCAN_PER / 4; ++k) {
        int4 v = *(const int4*)(cnt + lo + k * 4);
        if (PAD > 1) {
            v.x = (v.x + PAD - 1) & ~(PAD - 1);
            v.y = (v.y + PAD - 1) & ~(PAD - 1);
            v.z = (v.z + PAD - 1) & ~(PAD - 1);
            v.w = (v.w + PAD - 1) & ~(PAD - 1);
        }
        c[k] = v;
        s += v.x + v.y + v.z + v.w;
    }
    int lane = t & 63, wid = t >> 6;
    int v = s;
    #pragma unroll
    for (int d = 1; d < 64; d <<= 1) {
        int u = __shfl_up(v, d);
        if (lane >= d) v += u;
    }
    __shared__ int wtot[16], woff[16];
    if (lane == 63) wtot[wid] = v;
    __syncthreads();
    if (t == 0) {
        int acc = 0;
        #pragma unroll
        for (int w = 0; w < 16; ++w) { woff[w] = acc; acc += wtot[w]; }
    }
    __syncthreads();
    int base = woff[wid] + v - s;
    #pragma unroll
    for (int k = 0; k < SCAN_PER / 4; ++k) {
        int i = lo + k * 4;
        if (i     <= NSUP) rp[i]     = base;  base += c[k].x;
        if (i + 1 <= NSUP) rp[i + 1] = base;  base += c[k].y;
        if (i + 2 <= NSUP) rp[i + 2] = base;  base += c[k].z;
        if (i + 3 <= NSUP) rp[i + 3] = base;  base += c[k].w;
    }
}

// ---------------- pixel scatter ----------------
__global__ __launch_bounds__(256) void pix_scatter(const int* __restrict__ seg,
        const int* __restrict__ rp, int* __restrict__ fill, int* __restrict__ pix) {
    int p = blockIdx.x * 256 + threadIdx.x;
    if (p >= NPIX) return;
    int s = seg[p];
    int pos = rp[s] + atomicAdd(fill + s, 1);
    pix[pos] = p;
}

// ---------------- edge scatter: interleaved (src, w) pairs ----------------
__global__ __launch_bounds__(256) void edge_scatter(const int* __restrict__ srcv,
        const int* __restrict__ dstv, const float* __restrict__ w,
        const int* __restrict__ rp, int* __restrict__ fill, int2* __restrict__ epk) {
    int e = blockIdx.x * 256 + threadIdx.x;
    if (e >= NE) return;
    int d = dstv[e];
    int pos = rp[d] + atomicAdd(fill + d, 1);
    epk[pos] = make_int2(srcv[e], __float_as_int(w[e]));
}

// ---------------- pooling: half-wave per superpixel, float4 lanes, 2-pixel unroll ----------------
__global__ __launch_bounds__(256) void pool_gather(const float* __restrict__ x,
        const int* __restrict__ pp, const int* __restrict__ pix, float* __restrict__ h) {
    const int tid = threadIdx.x;
    const int wave = tid >> 6, lane = tid & 63;
    const int hf = lane >> 5, hl = lane & 31;
    const int row = blockIdx.x * 8 + wave * 2 + hf;
    const int j0 = pp[row], j1 = pp[row + 1];
    float4 a0 = make_float4(0.f, 0.f, 0.f, 0.f);
    float4 a1 = make_float4(0.f, 0.f, 0.f, 0.f);
    int j = j0;
    for (; j + 1 < j1; j += 2) {
        int p0 = pix[j], p1 = pix[j + 1];
        float4 v0 = *(const float4*)(x + rowoff(p0) + hl * 4);
        float4 v1 = *(const float4*)(x + rowoff(p1) + hl * 4);
        a0.x += v0.x; a0.y += v0.y; a0.z += v0.z; a0.w += v0.w;
        a1.x += v1.x; a1.y += v1.y; a1.z += v1.z; a1.w += v1.w;
    }
    if (j < j1) {
        int p0 = pix[j];
        float4 v0 = *(const float4*)(x + rowoff(p0) + hl * 4);
        a0.x += v0.x; a0.y += v0.y; a0.z += v0.z; a0.w += v0.w;
    }
    float inv = 1.0f / fmaxf((float)(j1 - j0), 1.0f);
    float4 o = make_float4((a0.x + a1.x) * inv, (a0.y + a1.y) * inv,
                           (a0.z + a1.z) * inv, (a0.w + a1.w) * inv);
    *(float4*)(h + rowoff(row) + hl * 4) = o;
}

// ---------------- GEMM: z = act(hin) @ W + b ; y0 = bf16(act(hin) + z) ----------------
// FUSE=1: act(v) = leaky(v*sc + sh)  (BN of previous layer applied on load)
template <int FUSE>
__global__ __launch_bounds__(256) void gemm_bias(const float* __restrict__ hin,
        const float* __restrict__ scsh, const float* __restrict__ W,
        const float* __restrict__ bias,
        unsigned short* __restrict__ zb, unsigned short* __restrict__ y0) {
    __shared__ float hs[32 * DD];   // 16 KB
    __shared__ float Ws[64 * DD];   // 32 KB
    const int tid = threadIdx.x;
    const int r0 = blockIdx.x * 32;
    {
        for (int i = tid; i < 32 * DD / 4; i += 256) {
            int row = i >> 5;
            float4 v = make_float4(0.f, 0.f, 0.f, 0.f);
            if (r0 + row < NSUP) v = *(const float4*)(hin + rowoff(r0 + row) + (i & 31) * 4);
            if (FUSE) {
                float4 scv = *(const float4*)(scsh + (i & 31) * 4);
                float4 shv = *(const float4*)(scsh + 128 + (i & 31) * 4);
                v.x = lrelu(fmaf(v.x, scv.x, shv.x));
                v.y = lrelu(fmaf(v.y, scv.y, shv.y));
                v.z = lrelu(fmaf(v.z, scv.z, shv.z));
                v.w = lrelu(fmaf(v.w, scv.w, shv.w));
            }
            *(float4*)(hs + i * 4) = v;
        }
    }
    const int cg = tid & 31;
    const int rg = tid >> 5;
    float acc[4][4];
    #pragma unroll
    for (int i = 0; i < 4; ++i)
        #pragma unroll
        for (int j = 0; j < 4; ++j) acc[i][j] = 0.f;

    for (int k0 = 0; k0 < DD; k0 += 64) {
        __syncthreads();
        for (int i = tid; i < 64 * DD / 4; i += 256)
            *(float4*)(Ws + i * 4) = *(const float4*)(W + (size_t)k0 * DD + i * 4);
        __syncthreads();
        #pragma unroll 8
        for (int k = 0; k < 64; ++k) {
            float4 wv = *(const float4*)(Ws + k * DD + cg * 4);
            #pragma unroll
            for (int i = 0; i < 4; ++i) {
                float hv = hs[(rg * 4 + i) * DD + k0 + k];
                acc[i][0] = fmaf(hv, wv.x, acc[i][0]);
                acc[i][1] = fmaf(hv, wv.y, acc[i][1]);
                acc[i][2] = fmaf(hv, wv.z, acc[i][2]);
                acc[i][3] = fmaf(hv, wv.w, acc[i][3]);
            }
        }
    }
    float4 bv = *(const float4*)(bias + cg * 4);
    #pragma unroll
    for (int i = 0; i < 4; ++i) {
        int r = r0 + rg * 4 + i;
        if (r < NSUP) {
            float4 o = make_float4(acc[i][0] + bv.x, acc[i][1] + bv.y,
                                   acc[i][2] + bv.z, acc[i][3] + bv.w);
            // z (bf16)
            unsigned int z0 = (unsigned int)f2bf(o.x) | ((unsigned int)f2bf(o.y) << 16);
            unsigned int z1 = (unsigned int)f2bf(o.z) | ((unsigned int)f2bf(o.w) << 16);
            *(uint2*)(zb + rowoff(r) + cg * 4) = make_uint2(z0, z1);
            // y0 = h + z (bf16)
            float h0 = hs[(rg * 4 + i) * DD + cg * 4 + 0];
            float h1 = hs[(rg * 4 + i) * DD + cg * 4 + 1];
            float h2 = hs[(rg * 4 + i) * DD + cg * 4 + 2];
            float h3 = hs[(rg * 4 + i) * DD + cg * 4 + 3];
            unsigned int p0 = (unsigned int)f2bf(h0 + o.x) | ((unsigned int)f2bf(h1 + o.y) << 16);
            unsigned int p1 = (unsigned int)f2bf(h2 + o.z) | ((unsigned int)f2bf(h3 + o.w) << 16);
            *(uint2*)(y0 + rowoff(r) + cg * 4) = make_uint2(p0, p1);
        }
    }
}

// ---------------- SpMM: quarter-wave (16 lanes x 16B) per row, 2-edge packets ----------------
// FINAL=0: yout = bf16( (A@y)*INV_C + zb )
// FINAL=1: xi5  = (A@y)*INV_C   (f32)
template <int FINAL>
__global__ __launch_bounds__(256) void spmm_q(const unsigned short* __restrict__ yin,
        const int* __restrict__ rp, const int2* __restrict__ epk,
        const unsigned short* __restrict__ zb, float* __restrict__ xi5,
        unsigned short* __restrict__ yout) {
    const int tid = threadIdx.x;
    const int wave = tid >> 6, lane = tid & 63;
    const int q = lane >> 4, ql = lane & 15;
    const int row = blockIdx.x * 16 + wave * 4 + q;
    const int j0 = rp[row], j1 = rp[row + 1];
    float a0 = 0.f, a1 = 0.f, a2 = 0.f, a3 = 0.f;
    float a4 = 0.f, a5 = 0.f, a6 = 0.f, a7 = 0.f;
    const size_t fo = (size_t)ql * 8;
    for (int j = j0; j < j1; j += 2) {
        int4 e = *(const int4*)(epk + j);               // (s0,w0,s1,w1) - 16B aligned (j even)
        uint4 v0 = *(const uint4*)(yin + rowoff(e.x) + fo);
        uint4 v1 = *(const uint4*)(yin + rowoff(e.z) + fo);
        float w0 = __int_as_float(e.y), w1 = __int_as_float(e.w);
        a0 = fmaf(w0, bf2f_lo(v0.x), a0); a1 = fmaf(w0, bf2f_hi(v0.x), a1);
        a2 = fmaf(w0, bf2f_lo(v0.y), a2); a3 = fmaf(w0, bf2f_hi(v0.y), a3);
        a4 = fmaf(w0, bf2f_lo(v0.z), a4); a5 = fmaf(w0, bf2f_hi(v0.z), a5);
        a6 = fmaf(w0, bf2f_lo(v0.w), a6); a7 = fmaf(w0, bf2f_hi(v0.w), a7);
        a0 = fmaf(w1, bf2f_lo(v1.x), a0); a1 = fmaf(w1, bf2f_hi(v1.x), a1);
        a2 = fmaf(w1, bf2f_lo(v1.y), a2); a3 = fmaf(w1, bf2f_hi(v1.y), a3);
        a4 = fmaf(w1, bf2f_lo(v1.z), a4); a5 = fmaf(w1, bf2f_hi(v1.z), a5);
        a6 = fmaf(w1, bf2f_lo(v1.w), a6); a7 = fmaf(w1, bf2f_hi(v1.w), a7);
    }
    a0 *= INV_C; a1 *= INV_C; a2 *= INV_C; a3 *= INV_C;
    a4 *= INV_C; a5 *= INV_C; a6 *= INV_C; a7 *= INV_C;
    if (FINAL) {
        *(float4*)(xi5 + rowoff(row) + fo)     = make_float4(a0, a1, a2, a3);
        *(float4*)(xi5 + rowoff(row) + fo + 4) = make_float4(a4, a5, a6, a7);
    } else {
        uint4 zv = *(const uint4*)(zb + rowoff(row) + fo);
        a0 += bf2f_lo(zv.x); a1 += bf2f_hi(zv.x);
        a2 += bf2f_lo(zv.y); a3 += bf2f_hi(zv.y);
        a4 += bf2f_lo(zv.z); a5 += bf2f_hi(zv.z);
        a6 += bf2f_lo(zv.w); a7 += bf2f_hi(zv.w);
        uint4 o;
        o.x = (unsigned int)f2bf(a0) | ((unsigned int)f2bf(a1) << 16);
        o.y = (unsigned int)f2bf(a2) | ((unsigned int)f2bf(a3) << 16);
        o.z = (unsigned int)f2bf(a4) | ((unsigned int)f2bf(a5) << 16);
        o.w = (unsigned int)f2bf(a6) | ((unsigned int)f2bf(a7) << 16);
        *(uint4*)(yout + rowoff(row) + fo) = o;
    }
}

// ---------------- BatchNorm stats (vectorized) ----------------
__global__ __launch_bounds__(256) void bn_stats(const float* __restrict__ xi,
        float* __restrict__ sums) {
    const int cg = threadIdx.x & 31;    // channel group (4 ch)
    const int rs = threadIdx.x >> 5;    // row slot (8)
    float4 s = make_float4(0.f, 0.f, 0.f, 0.f);
    float4 qq = make_float4(0.f, 0.f, 0.f, 0.f);
    for (int r = blockIdx.x * 8 + rs; r < NSUP; r += gridDim.x * 8) {
        float4 v = *(const float4*)(xi + rowoff(r) + cg * 4);
        s.x += v.x; s.y += v.y; s.z += v.z; s.w += v.w;
        qq.x = fmaf(v.x, v.x, qq.x); qq.y = fmaf(v.y, v.y, qq.y);
        qq.z = fmaf(v.z, v.z, qq.z); qq.w = fmaf(v.w, v.w, qq.w);
    }
    __shared__ float4 ls[256], lq[256];
    ls[threadIdx.x] = s; lq[threadIdx.x] = qq;
    __syncthreads();
    if (rs == 0) {
        #pragma unroll
        for (int k = 1; k < 8; ++k) {
            float4 ts = ls[k * 32 + cg], tq = lq[k * 32 + cg];
            s.x += ts.x; s.y += ts.y; s.z += ts.z; s.w += ts.w;
            qq.x += tq.x; qq.y += tq.y; qq.z += tq.z; qq.w += tq.w;
        }
        atomicAdd(&sums[cg * 4 + 0], s.x); atomicAdd(&sums[cg * 4 + 1], s.y);
        atomicAdd(&sums[cg * 4 + 2], s.z); atomicAdd(&sums[cg * 4 + 3], s.w);
        atomicAdd(&sums[128 + cg * 4 + 0], qq.x); atomicAdd(&sums[128 + cg * 4 + 1], qq.y);
        atomicAdd(&sums[128 + cg * 4 + 2], qq.z); atomicAdd(&sums[128 + cg * 4 + 3], qq.w);
    }
}

// computes sc/sh, then zeroes stats for the next layer
__global__ void bn_finalize(float* __restrict__ sums, const float* __restrict__ gamma,
        const float* __restrict__ beta, float* __restrict__ sc) {
    int c = threadIdx.x;
    float mean = sums[c] * (1.0f / NSUP);
    float var = sums[128 + c] * (1.0f / NSUP) - mean * mean;
    float scale = gamma[c] / sqrtf(var + BN_EPS_C);
    sc[c] = scale;
    sc[128 + c] = beta[c] - mean * scale;
    __syncthreads();
    sums[c] = 0.f;
    sums[128 + c] = 0.f;
}

// final-layer BN apply (xi5 -> h), h feeds unpool
__global__ __launch_bounds__(256) void bn_apply(const float* __restrict__ xi,
        const float* __restrict__ sc, float* __restrict__ h) {
    int t = blockIdx.x * 256 + threadIdx.x;
    int r = t >> 5, l = t & 31;
    if (r >= NSUP) return;
    float4 v = *(const float4*)(xi + rowoff(r) + l * 4);
    float4 scv = *(const float4*)(sc + l * 4);
    float4 shv = *(const float4*)(sc + 128 + l * 4);
    v.x = lrelu(fmaf(v.x, scv.x, shv.x));
    v.y = lrelu(fmaf(v.y, scv.y, shv.y));
    v.z = lrelu(fmaf(v.z, scv.z, shv.z));
    v.w = lrelu(fmaf(v.w, scv.w, shv.w));
    *(float4*)(h + rowoff(r) + l * 4) = v;
}

// ---------------- unpool ----------------
__global__ __launch_bounds__(256) void unpool(const float* __restrict__ h,
        const int* __restrict__ seg, float* __restrict__ out) {
    int t = blockIdx.x * 256 + threadIdx.x;
    int p = t >> 5, l = t & 31;
    if (p >= NPIX) return;
    int s = seg[p];
    float4 v = *(const float4*)(h + rowoff(s) + l * 4);
    *(float4*)(out + rowoff(p) + l * 4) = v;
}

extern "C" void kernel_launch(void* const* d_in, const int* in_sizes, int n_in,
                              void* d_out, int out_size, void* d_ws, size_t ws_size,
                              hipStream_t stream) {
    const float* x     = (const float*)d_in[0];
    const float* W     = (const float*)d_in[1];
    const float* b     = (const float*)d_in[2];
    const float* gamma = (const float*)d_in[3];
    const float* beta  = (const float*)d_in[4];
    const float* ewt   = (const float*)d_in[5];
    const int*   seg   = (const int*)d_in[6];
    const int*   eidx  = (const int*)d_in[7];
    const int*   esrc  = eidx;
    const int*   edst  = eidx + NE;
    float* out = (float*)d_out;

    // d_out hosts transients (all dead before final unpool):
    //   xi5 f32 25.6MB | zb bf16 12.8MB | ya bf16 12.8MB | yb bf16 12.8MB  (64MB < 128MB)
    const size_t MAT = (size_t)NSUP * DD;
    float* xi5 = out;
    unsigned short* zb = (unsigned short*)(out + MAT);
    unsigned short* ya = zb + MAT;
    unsigned short* yb = ya + MAT;

    char* ws = (char*)d_ws;
    size_t off = 0;
    auto alloc = [&](size_t bytes) -> void* {
        void* p = ws + off;
        off = (off + bytes + 255) & ~(size_t)255;
        return p;
    };
    float* h       = (float*)alloc(sizeof(float) * MAT);       // 25.6 MB
    int*   rowcnt  = (int*)alloc(sizeof(int) * CNT_CAP);
    int*   rowptr  = (int*)alloc(sizeof(int) * (NSUP + 1));
    int*   rowfill = (int*)alloc(sizeof(int) * NSUP);
    int*   pixcnt  = (int*)alloc(sizeof(int) * CNT_CAP);
    int*   pixptr  = (int*)alloc(sizeof(int) * (NSUP + 1));
    int*   pixfill = (int*)alloc(sizeof(int) * NSUP);
    int*   pixids  = (int*)alloc(sizeof(int) * NPIX);          // 1 MB
    int2*  epk     = (int2*)alloc(sizeof(int2) * NEPAD2);      // 6.8 MB
    float* stats   = (float*)alloc(sizeof(float) * 256);
    float* sc      = (float*)alloc(sizeof(float) * 256);

    hipMemsetAsync(rowcnt, 0, sizeof(int) * CNT_CAP, stream);
    hipMemsetAsync(rowfill, 0, sizeof(int) * NSUP, stream);
    hipMemsetAsync(pixcnt, 0, sizeof(int) * CNT_CAP, stream);
    hipMemsetAsync(pixfill, 0, sizeof(int) * NSUP, stream);
    hipMemsetAsync(epk, 0, sizeof(int2) * NEPAD2, stream);     // pad -> (src 0, w 0.0)
    hipMemsetAsync(stats, 0, sizeof(float) * 256, stream);

    // pixel CSR + pooling
    hist_k<<<(NPIX + 255) / 256, 256, 0, stream>>>(seg, pixcnt, NPIX);
    scan_rowptr<1><<<1, 1024, 0, stream>>>(pixcnt, pixptr);
    pix_scatter<<<(NPIX + 255) / 256, 256, 0, stream>>>(seg, pixptr, pixfill, pixids);
    pool_gather<<<NSUP / 8, 256, 0, stream>>>(x, pixptr, pixids, h);

    // edge CSR by dst, rows padded to multiple of 2, interleaved (src,w)
    hist_k<<<(NE + 255) / 256, 256, 0, stream>>>(edst, rowcnt, NE);
    scan_rowptr<2><<<1, 1024, 0, stream>>>(rowcnt, rowptr);
    edge_scatter<<<(NE + 255) / 256, 256, 0, stream>>>(esrc, edst, ewt, rowptr, rowfill, epk);

    // 5 SFNet layers.  y_t = xi_t + z (bf16); xi_{t+1} = A y_t / 2.9.
    // BN+leaky of layer i is fused into layer i+1's GEMM operand load.
    for (int i = 0; i < NL; ++i) {
        if (i == 0)
            gemm_bias<0><<<(NSUP + 31) / 32, 256, 0, stream>>>(h, nullptr,
                    W + (size_t)i * DD * DD, b + i * DD, zb, ya);
        else
            gemm_bias<1><<<(NSUP + 31) / 32, 256, 0, stream>>>(xi5, sc,
                    W + (size_t)i * DD * DD, b + i * DD, zb, ya);

        const unsigned short* ycur = ya;
        unsigned short* ynxt = yb;
        for (int t = 0; t < 4; ++t) {
            spmm_q<0><<<NSUP / 16, 256, 0, stream>>>(ycur, rowptr, epk, zb, nullptr, ynxt);
            const unsigned short* tmp = ycur;
            ycur = ynxt;
            ynxt = (unsigned short*)tmp;
        }
        spmm_q<1><<<NSUP / 16, 256, 0, stream>>>(ycur, rowptr, epk, nullptr, xi5, nullptr);

        bn_stats<<<256, 256, 0, stream>>>(xi5, stats);
        bn_finalize<<<1, 128, 0, stream>>>(stats, gamma + i * DD, beta + i * DD, sc);
    }

    // final layer: BN apply into h (ws), then unpool (overwrites all of d_out)
    bn_apply<<<NSUP * 32 / 256, 256, 0, stream>>>(xi5, sc, h);
    unpool<<<NPIX * 32 / 256, 256, 0, stream>>>(h, seg, out);
}